// Round 1
// baseline (726.613 us; speedup 1.0000x reference)
//
#include <hip/hip_runtime.h>

#define BB 32
#define TT 243
#define JJ 17
#define CC 256
#define BJC (BB*JJ)          // 544
#define MM (BJC*TT)          // 132192 rows (bj-major: r = bj*TT + t)
#define SIMP 244             // padded sim row stride (16B-aligned rows)
#define NEG_INF (-3.0e38f)

typedef __attribute__((ext_vector_type(8))) short bf16x8;
typedef __attribute__((ext_vector_type(4))) float f32x4;

__device__ __forceinline__ unsigned short f2bf(float f) {
  unsigned int u = __float_as_uint(f);
  u = (u + 0x7fffu + ((u >> 16) & 1u)) >> 16;   // RNE
  return (unsigned short)u;
}
__device__ __forceinline__ float bf2f(unsigned short s) {
  return __uint_as_float(((unsigned int)s) << 16);
}

// ---------- K0a: x [B,T,J,C] f32 -> xbf [BJ,T,C] bf16 ----------
__global__ void k_prep_x(const float* __restrict__ x, unsigned short* __restrict__ xbf) {
  int g = blockIdx.x * 256 + threadIdx.x;          // one float4 per thread
  if (g >= MM * (CC/4)) return;
  int c4  = g & 63;
  int rowx = g >> 6;                               // (b*TT + t)*JJ + j
  int b   = rowx / (TT*JJ);
  int rem = rowx - b*(TT*JJ);
  int t   = rem / JJ;
  int j   = rem - t*JJ;
  int rd  = (b*JJ + j)*TT + t;
  float4 v = *reinterpret_cast<const float4*>(x + (size_t)rowx*CC + c4*4);
  ushort4 o;
  o.x = f2bf(v.x); o.y = f2bf(v.y); o.z = f2bf(v.z); o.w = f2bf(v.w);
  *reinterpret_cast<ushort4*>(xbf + (size_t)rd*CC + c4*4) = o;
}

// ---------- K0b: W_u,W_v f32 [C,C] -> wc bf16 [512,C] ----------
__global__ void k_prep_w(const float* __restrict__ Wu, const float* __restrict__ Wv,
                         unsigned short* __restrict__ wc) {
  int g = blockIdx.x * 256 + threadIdx.x;
  if (g >= 512 * (CC/4)) return;
  int c4 = g & 63;
  int n  = g >> 6;
  const float* src = (n < CC) ? (Wu + (size_t)n*CC) : (Wv + (size_t)(n-CC)*CC);
  float4 v = *reinterpret_cast<const float4*>(src + c4*4);
  ushort4 o;
  o.x = f2bf(v.x); o.y = f2bf(v.y); o.z = f2bf(v.z); o.w = f2bf(v.w);
  *reinterpret_cast<ushort4*>(wc + (size_t)n*CC + c4*4) = o;
}

// ---------- K1: u,v = x @ W^T + b   (bf16 MFMA, 128x128 tile, 4 waves) ----------
__launch_bounds__(256)
__global__ void k_uv(const unsigned short* __restrict__ xbf,
                     const unsigned short* __restrict__ wc,
                     const float* __restrict__ bu, const float* __restrict__ bv,
                     unsigned short* __restrict__ uo, unsigned short* __restrict__ vo) {
  __shared__ unsigned short Al[128][40];   // +8 pad
  __shared__ unsigned short Bl[128][40];
  const int tid  = threadIdx.x;
  const int lane = tid & 63, wid = tid >> 6;
  const int wm = (wid >> 1) * 64, wn = (wid & 1) * 64;
  const int m0 = blockIdx.x * 128, n0 = blockIdx.y * 128;

  f32x4 acc[4][4];
  #pragma unroll
  for (int i = 0; i < 4; i++)
    #pragma unroll
    for (int j = 0; j < 4; j++) acc[i][j] = (f32x4){0.f, 0.f, 0.f, 0.f};

  for (int ks = 0; ks < CC; ks += 32) {
    #pragma unroll
    for (int it = 0; it < 2; ++it) {
      int s = tid + it * 256;                      // 512 16B-slots each for A and B
      int r = s >> 2, kq = s & 3;
      int gm = m0 + r; if (gm > MM - 1) gm = MM - 1;
      *reinterpret_cast<uint4*>(&Al[r][kq * 8]) =
        *reinterpret_cast<const uint4*>(xbf + (size_t)gm * CC + ks + kq * 8);
      int gn = n0 + r;                             // always < 512
      *reinterpret_cast<uint4*>(&Bl[r][kq * 8]) =
        *reinterpret_cast<const uint4*>(wc + (size_t)gn * CC + ks + kq * 8);
    }
    __syncthreads();
    const int kf = (lane >> 4) * 8;                // consistent k-slot map for A and B
    bf16x8 af[4], bfv[4];
    #pragma unroll
    for (int i = 0; i < 4; i++)
      af[i] = *reinterpret_cast<const bf16x8*>(&Al[wm + i * 16 + (lane & 15)][kf]);
    #pragma unroll
    for (int j = 0; j < 4; j++)
      bfv[j] = *reinterpret_cast<const bf16x8*>(&Bl[wn + j * 16 + (lane & 15)][kf]);
    #pragma unroll
    for (int i = 0; i < 4; i++)
      #pragma unroll
      for (int j = 0; j < 4; j++)
        acc[i][j] = __builtin_amdgcn_mfma_f32_16x16x32_bf16(af[i], bfv[j], acc[i][j], 0, 0, 0);
    __syncthreads();
  }

  float bias[4];
  #pragma unroll
  for (int j = 0; j < 4; j++) {
    int gn = n0 + wn + j * 16 + (lane & 15);
    bias[j] = (gn < CC) ? bu[gn] : bv[gn - CC];
  }
  const int rq = (lane >> 4) * 4;                  // C/D: col=lane&15, row=(lane>>4)*4+q
  #pragma unroll
  for (int i = 0; i < 4; i++) {
    #pragma unroll
    for (int q = 0; q < 4; q++) {
      int gm = m0 + wm + i * 16 + rq + q;
      if (gm < MM) {
        #pragma unroll
        for (int j = 0; j < 4; j++) {
          int gn = n0 + wn + j * 16 + (lane & 15);
          float val = acc[i][j][q] + bias[j];
          if (gn < CC) uo[(size_t)gm * CC + gn] = f2bf(val);
          else         vo[(size_t)gm * CC + gn - CC] = f2bf(val);
        }
      }
    }
  }
}

// ---------- K2: sim = xr @ xr^T per bj, fp32 VALU, 128x128 tile, 8x8/thread ----------
__launch_bounds__(256)
__global__ void k_sim(const float* __restrict__ x, float* __restrict__ sim) {
  __shared__ float AT[32][132];                    // [k][row], +4 pad
  __shared__ float BT[32][140];                    // [k][w(col)], w(c)=c+4*(c>>5)
  const int bj = blockIdx.x;
  const int n0 = blockIdx.y * 128;
  const int m0 = blockIdx.z * 128;
  const int b = bj / JJ, jj = bj - b * JJ;
  const float* xb = x + ((size_t)b * TT * JJ + jj) * CC;   // + t*(JJ*CC) + k
  const int tid = threadIdx.x;
  const int tx = tid & 15, ty = tid >> 4;

  float acc[8][8];
  #pragma unroll
  for (int i = 0; i < 8; i++)
    #pragma unroll
    for (int q = 0; q < 8; q++) acc[i][q] = 0.f;

  for (int ks = 0; ks < CC; ks += 32) {
    #pragma unroll
    for (int it = 0; it < 4; ++it) {
      int s = tid + it * 256;                      // 1024 slots: 128 rows x 8 kq
      int kq = s & 7, r = s >> 3;
      {
        int t = n0 + r; if (t > TT - 1) t = TT - 1;
        float4 v = *reinterpret_cast<const float4*>(xb + (size_t)t * (JJ * CC) + ks + kq * 4);
        AT[kq * 4 + 0][r] = v.x; AT[kq * 4 + 1][r] = v.y;
        AT[kq * 4 + 2][r] = v.z; AT[kq * 4 + 3][r] = v.w;
      }
      {
        int t = m0 + r; if (t > TT - 1) t = TT - 1;
        float4 v = *reinterpret_cast<const float4*>(xb + (size_t)t * (JJ * CC) + ks + kq * 4);
        int pc = r + 4 * (r >> 5);
        BT[kq * 4 + 0][pc] = v.x; BT[kq * 4 + 1][pc] = v.y;
        BT[kq * 4 + 2][pc] = v.z; BT[kq * 4 + 3][pc] = v.w;
      }
    }
    __syncthreads();
    const int pa = ty * 8;
    const int pb = 8 * tx + 4 * (tx >> 2);         // w(8tx); w(8tx+4)=pb+4
    #pragma unroll 4
    for (int k = 0; k < 32; k++) {
      float4 a0 = *reinterpret_cast<const float4*>(&AT[k][pa]);
      float4 a1 = *reinterpret_cast<const float4*>(&AT[k][pa + 4]);
      float4 b0 = *reinterpret_cast<const float4*>(&BT[k][pb]);
      float4 b1 = *reinterpret_cast<const float4*>(&BT[k][pb + 4]);
      float av[8] = {a0.x, a0.y, a0.z, a0.w, a1.x, a1.y, a1.z, a1.w};
      float bv[8] = {b0.x, b0.y, b0.z, b0.w, b1.x, b1.y, b1.z, b1.w};
      #pragma unroll
      for (int i = 0; i < 8; i++)
        #pragma unroll
        for (int q = 0; q < 8; q++)
          acc[i][q] = __builtin_fmaf(av[i], bv[q], acc[i][q]);
    }
    __syncthreads();
  }

  const size_t base = (size_t)bj * TT * SIMP;
  const int c0 = m0 + tx * 8;
  #pragma unroll
  for (int i = 0; i < 8; i++) {
    int n = n0 + ty * 8 + i;
    if (n < TT) {
      if (c0 < TT)
        *reinterpret_cast<float4*>(sim + base + (size_t)n * SIMP + c0) =
          (float4){acc[i][0], acc[i][1], acc[i][2], acc[i][3]};
      if (c0 + 4 < TT)
        *reinterpret_cast<float4*>(sim + base + (size_t)n * SIMP + c0 + 4) =
          (float4){acc[i][4], acc[i][5], acc[i][6], acc[i][7]};
    }
  }
}

// ---------- K3a: per row: thr = 4th largest, deg = count(sim>=thr) ----------
__global__ void k_topk(const float* __restrict__ sim,
                       float* __restrict__ thr_o, float* __restrict__ dis_o) {
  int r = blockIdx.x;                              // 0..MM-1
  int l = threadIdx.x;                             // 64 = one wave
  const float* row = sim + (size_t)r * SIMP;
  float v0 = (l       < TT) ? row[l]       : NEG_INF;
  float v1 = (l + 64  < TT) ? row[l + 64]  : NEG_INF;
  float v2 = (l + 128 < TT) ? row[l + 128] : NEG_INF;
  float v3 = (l + 192 < TT) ? row[l + 192] : NEG_INF;
  // sort desc in-lane
  { float mx, mn;
    mx=fmaxf(v0,v1); mn=fminf(v0,v1); v0=mx; v1=mn;
    mx=fmaxf(v2,v3); mn=fminf(v2,v3); v2=mx; v3=mn;
    mx=fmaxf(v0,v2); mn=fminf(v0,v2); v0=mx; v2=mn;
    mx=fmaxf(v1,v3); mn=fminf(v1,v3); v1=mx; v3=mn;
    mx=fmaxf(v1,v2); mn=fminf(v1,v2); v1=mx; v2=mn; }
  int p = 0;
  float thr = NEG_INF;
  #pragma unroll
  for (int it = 0; it < 4; ++it) {                 // extract one max instance per round
    float head = (p == 0) ? v0 : (p == 1) ? v1 : (p == 2) ? v2 : (p == 3) ? v3 : NEG_INF;
    float m = head;
    #pragma unroll
    for (int off = 1; off < 64; off <<= 1) m = fmaxf(m, __shfl_xor(m, off));
    thr = m;
    unsigned long long msk = __ballot(head == m);
    int first = __ffsll(msk) - 1;
    if (l == first) p++;
  }
  int cnt = (v0 >= thr) + (v1 >= thr) + (v2 >= thr) + (v3 >= thr);
  #pragma unroll
  for (int off = 1; off < 64; off <<= 1) cnt += __shfl_xor(cnt, off);
  if (l == 0) { thr_o[r] = thr; dis_o[r] = rsqrtf((float)cnt); }
}

// ---------- K3b: h = norm_adj @ v + u ; per-row BN partials ----------
__launch_bounds__(256)
__global__ void k_agg(const float* __restrict__ sim, const float* __restrict__ thr,
                      const float* __restrict__ dis, const unsigned short* __restrict__ u,
                      const unsigned short* __restrict__ v, unsigned short* __restrict__ h,
                      float* __restrict__ p1, float* __restrict__ p2) {
  __shared__ int   nbr[TT];
  __shared__ float wgt[TT];
  __shared__ int   wcnt[4];
  __shared__ float red1[4], red2[4];
  const int r = blockIdx.x;
  const int bj = r / TT;
  const int tid = threadIdx.x, lane = tid & 63, wv = tid >> 6;
  const float tr = thr[r], dr = dis[r];
  bool f = false;
  if (tid < TT) f = (sim[(size_t)r * SIMP + tid] >= tr);
  unsigned long long msk = __ballot(f);
  int pre = __popcll(msk & ((1ull << lane) - 1ull));
  if (lane == 0) wcnt[wv] = __popcll(msk);
  __syncthreads();
  int base = 0;
  for (int i = 0; i < wv; i++) base += wcnt[i];
  const int total = wcnt[0] + wcnt[1] + wcnt[2] + wcnt[3];
  if (f) { nbr[base + pre] = tid; wgt[base + pre] = dr * dis[bj * TT + tid]; }
  __syncthreads();

  const int c = tid;                               // 256 channels
  const size_t rowoff = (size_t)r * CC;
  const size_t vbase  = (size_t)bj * TT * CC;
  float acc = bf2f(u[rowoff + c]);
  for (int e = 0; e < total; ++e)
    acc += wgt[e] * bf2f(v[vbase + (size_t)nbr[e] * CC + c]);
  h[rowoff + c] = f2bf(acc);

  float s1 = acc, s2 = acc * acc;
  #pragma unroll
  for (int off = 1; off < 64; off <<= 1) { s1 += __shfl_xor(s1, off); s2 += __shfl_xor(s2, off); }
  if (lane == 0) { red1[wv] = s1; red2[wv] = s2; }
  __syncthreads();
  if (tid == 0) {
    p1[r] = red1[0] + red1[1] + red1[2] + red1[3];
    p2[r] = red2[0] + red2[1] + red2[2] + red2[3];
  }
}

// ---------- K4: BN stats per t -> scale/shift ----------
__global__ void k_bnstat(const float* __restrict__ p1, const float* __restrict__ p2,
                         const float* __restrict__ gamma, const float* __restrict__ beta,
                         float* __restrict__ scale, float* __restrict__ shift) {
  __shared__ float sA[256], sB[256];
  const int t = blockIdx.x;                        // 0..TT-1
  const int tid = threadIdx.x;
  float a = 0.f, b2 = 0.f;
  for (int bj = tid; bj < BJC; bj += 256) {
    a  += p1[bj * TT + t];
    b2 += p2[bj * TT + t];
  }
  sA[tid] = a; sB[tid] = b2;
  __syncthreads();
  for (int s = 128; s > 0; s >>= 1) {
    if (tid < s) { sA[tid] += sA[tid + s]; sB[tid] += sB[tid + s]; }
    __syncthreads();
  }
  if (tid == 0) {
    const float invN = 1.0f / (float)(BJC * CC);
    float mean = sA[0] * invN;
    float var  = sB[0] * invN - mean * mean;
    float sc   = rsqrtf(var + 1e-5f) * gamma[t];
    scale[t] = sc;
    shift[t] = beta[t] - mean * sc;
  }
}

// ---------- K5: out = relu(x + h*scale + shift), back to [B,T,J,C] ----------
__global__ void k_out(const float* __restrict__ x, const unsigned short* __restrict__ h,
                      const float* __restrict__ scale, const float* __restrict__ shift,
                      float* __restrict__ out) {
  int g = blockIdx.x * 256 + threadIdx.x;
  if (g >= MM * (CC/4)) return;
  int c4  = g & 63;
  int rowx = g >> 6;                               // (b*TT + t)*JJ + j
  int b   = rowx / (TT*JJ);
  int rem = rowx - b*(TT*JJ);
  int t   = rem / JJ;
  int j   = rem - t*JJ;
  size_t hoff = ((size_t)(b*JJ + j) * TT + t) * CC + c4*4;
  float4 xv = *reinterpret_cast<const float4*>(x + (size_t)rowx*CC + c4*4);
  ushort4 hv = *reinterpret_cast<const ushort4*>(h + hoff);
  float sc = scale[t], sh = shift[t];
  float4 o;
  o.x = fmaxf(xv.x + bf2f(hv.x)*sc + sh, 0.f);
  o.y = fmaxf(xv.y + bf2f(hv.y)*sc + sh, 0.f);
  o.z = fmaxf(xv.z + bf2f(hv.z)*sc + sh, 0.f);
  o.w = fmaxf(xv.w + bf2f(hv.w)*sc + sh, 0.f);
  *reinterpret_cast<float4*>(out + (size_t)rowx*CC + c4*4) = o;
}

extern "C" void kernel_launch(void* const* d_in, const int* in_sizes, int n_in,
                              void* d_out, int out_size, void* d_ws, size_t ws_size,
                              hipStream_t stream) {
  const float* x     = (const float*)d_in[0];
  const float* Wu    = (const float*)d_in[1];
  const float* bu    = (const float*)d_in[2];
  const float* Wv    = (const float*)d_in[3];
  const float* bv    = (const float*)d_in[4];
  const float* gamma = (const float*)d_in[5];
  const float* beta  = (const float*)d_in[6];
  float* out = (float*)d_out;

  char* ws = (char*)d_ws;
  size_t off = 0;
  auto alloc = [&](size_t bytes) -> void* {
    void* p = ws + off;
    off = (off + bytes + 255) & ~(size_t)255;
    return p;
  };
  unsigned short* xbf = (unsigned short*)alloc((size_t)MM * CC * 2);
  unsigned short* u   = (unsigned short*)alloc((size_t)MM * CC * 2);
  unsigned short* v   = (unsigned short*)alloc((size_t)MM * CC * 2);
  unsigned short* h   = (unsigned short*)alloc((size_t)MM * CC * 2);
  unsigned short* wc  = (unsigned short*)alloc((size_t)512 * CC * 2);
  float* sim   = (float*)alloc((size_t)BJC * TT * SIMP * 4);
  float* thr   = (float*)alloc((size_t)MM * 4);
  float* dis   = (float*)alloc((size_t)MM * 4);
  float* p1    = (float*)alloc((size_t)MM * 4);
  float* p2    = (float*)alloc((size_t)MM * 4);
  float* scale = (float*)alloc(1024);
  float* shift = (float*)alloc(1024);

  if (ws_size < off) {                             // clean failure signal, no OOB
    hipMemsetAsync(d_out, 0, (size_t)out_size * 4, stream);
    return;
  }

  k_prep_x<<<dim3((MM*(CC/4) + 255)/256), dim3(256), 0, stream>>>(x, xbf);
  k_prep_w<<<dim3((512*(CC/4) + 255)/256), dim3(256), 0, stream>>>(Wu, Wv, wc);
  k_uv   <<<dim3((MM + 127)/128, 4), dim3(256), 0, stream>>>(xbf, wc, bu, bv, u, v);
  k_sim  <<<dim3(BJC, 2, 2), dim3(256), 0, stream>>>(x, sim);
  k_topk <<<dim3(MM), dim3(64), 0, stream>>>(sim, thr, dis);
  k_agg  <<<dim3(MM), dim3(256), 0, stream>>>(sim, thr, dis, u, v, h, p1, p2);
  k_bnstat<<<dim3(TT), dim3(256), 0, stream>>>(p1, p2, gamma, beta, scale, shift);
  k_out  <<<dim3((MM*(CC/4) + 255)/256), dim3(256), 0, stream>>>(x, h, scale, shift, out);
}

// Round 2
// 576.525 us; speedup vs baseline: 1.2603x; 1.2603x over previous
//
#include <hip/hip_runtime.h>

#define BB 32
#define TT 243
#define JJ 17
#define CC 256
#define BJC (BB*JJ)          // 544
#define MM (BJC*TT)          // 132192 rows (bj-major: r = bj*TT + t)
#define SIMP 244             // padded sim row stride (16B-aligned rows)
#define NEG_INF (-3.0e38f)

typedef __attribute__((ext_vector_type(8))) short bf16x8;
typedef __attribute__((ext_vector_type(4))) float f32x4;

__device__ __forceinline__ unsigned short f2bf(float f) {
  unsigned int u = __float_as_uint(f);
  u = (u + 0x7fffu + ((u >> 16) & 1u)) >> 16;   // RNE
  return (unsigned short)u;
}
__device__ __forceinline__ float bf2f(unsigned short s) {
  return __uint_as_float(((unsigned int)s) << 16);
}

// ---------- K0b: W_u,W_v f32 [C,C] -> wc bf16 [512,C] ----------
__global__ void k_prep_w(const float* __restrict__ Wu, const float* __restrict__ Wv,
                         unsigned short* __restrict__ wc) {
  int g = blockIdx.x * 256 + threadIdx.x;
  if (g >= 512 * (CC/4)) return;
  int c4 = g & 63;
  int n  = g >> 6;
  const float* src = (n < CC) ? (Wu + (size_t)n*CC) : (Wv + (size_t)(n-CC)*CC);
  float4 v = *reinterpret_cast<const float4*>(src + c4*4);
  ushort4 o;
  o.x = f2bf(v.x); o.y = f2bf(v.y); o.z = f2bf(v.z); o.w = f2bf(v.w);
  *reinterpret_cast<ushort4*>(wc + (size_t)n*CC + c4*4) = o;
}

// ---------- K1: u,v = x @ W^T + b  (bf16 MFMA, A converted from f32 on the fly) ----------
__launch_bounds__(256)
__global__ void k_uv(const float* __restrict__ x,
                     const unsigned short* __restrict__ wc,
                     const float* __restrict__ bu, const float* __restrict__ bv,
                     unsigned short* __restrict__ uo, unsigned short* __restrict__ vo) {
  __shared__ unsigned short Al[128][40];   // +8 pad
  __shared__ unsigned short Bl[128][40];
  const int tid  = threadIdx.x;
  const int lane = tid & 63, wid = tid >> 6;
  const int wm = (wid >> 1) * 64, wn = (wid & 1) * 64;
  const int m0 = blockIdx.x * 128, n0 = blockIdx.y * 128;

  // Precompute A-staging source rows (x is [B,T,J,C]; xr row r=bj*TT+t).
  const int kq8 = tid & 7;                  // 4-float quad within 32-k slice
  size_t arow[4];
  int r_it[4];
  #pragma unroll
  for (int it = 0; it < 4; ++it) {
    int r = (tid >> 3) + it * 32;
    r_it[it] = r;
    int gm = m0 + r; if (gm > MM - 1) gm = MM - 1;
    int bj = gm / TT, t = gm - bj * TT;
    int b = bj / JJ, j = bj - b * JJ;
    arow[it] = ((size_t)(b * TT + t) * JJ + j) * CC;
  }

  f32x4 acc[4][4];
  #pragma unroll
  for (int i = 0; i < 4; i++)
    #pragma unroll
    for (int j = 0; j < 4; j++) acc[i][j] = (f32x4){0.f, 0.f, 0.f, 0.f};

  for (int ks = 0; ks < CC; ks += 32) {
    #pragma unroll
    for (int it = 0; it < 4; ++it) {        // A: 128 rows x 32 k from f32 x
      float4 xv = *reinterpret_cast<const float4*>(x + arow[it] + ks + kq8 * 4);
      ushort4 o;
      o.x = f2bf(xv.x); o.y = f2bf(xv.y); o.z = f2bf(xv.z); o.w = f2bf(xv.w);
      *reinterpret_cast<ushort4*>(&Al[r_it[it]][kq8 * 4]) = o;
    }
    #pragma unroll
    for (int it = 0; it < 2; ++it) {        // B: 128 rows x 32 k bf16
      int s = tid + it * 256;
      int r = s >> 2, kq = s & 3;
      *reinterpret_cast<uint4*>(&Bl[r][kq * 8]) =
        *reinterpret_cast<const uint4*>(wc + (size_t)(n0 + r) * CC + ks + kq * 8);
    }
    __syncthreads();
    const int kf = (lane >> 4) * 8;
    bf16x8 af[4], bfv[4];
    #pragma unroll
    for (int i = 0; i < 4; i++)
      af[i] = *reinterpret_cast<const bf16x8*>(&Al[wm + i * 16 + (lane & 15)][kf]);
    #pragma unroll
    for (int j = 0; j < 4; j++)
      bfv[j] = *reinterpret_cast<const bf16x8*>(&Bl[wn + j * 16 + (lane & 15)][kf]);
    #pragma unroll
    for (int i = 0; i < 4; i++)
      #pragma unroll
      for (int j = 0; j < 4; j++)
        acc[i][j] = __builtin_amdgcn_mfma_f32_16x16x32_bf16(af[i], bfv[j], acc[i][j], 0, 0, 0);
    __syncthreads();
  }

  float bias[4];
  #pragma unroll
  for (int j = 0; j < 4; j++) {
    int gn = n0 + wn + j * 16 + (lane & 15);
    bias[j] = (gn < CC) ? bu[gn] : bv[gn - CC];
  }
  const int rq = (lane >> 4) * 4;                  // C/D: col=lane&15, row=(lane>>4)*4+q
  #pragma unroll
  for (int i = 0; i < 4; i++) {
    #pragma unroll
    for (int q = 0; q < 4; q++) {
      int gm = m0 + wm + i * 16 + rq + q;
      if (gm < MM) {
        #pragma unroll
        for (int j = 0; j < 4; j++) {
          int gn = n0 + wn + j * 16 + (lane & 15);
          float val = acc[i][j][q] + bias[j];
          if (gn < CC) uo[(size_t)gm * CC + gn] = f2bf(val);
          else         vo[(size_t)gm * CC + gn - CC] = f2bf(val);
        }
      }
    }
  }
}

// ---------- K2: sim = xr @ xr^T per bj, fp32 VALU, 128x128 tile, 8x8/thread ----------
__launch_bounds__(256)
__global__ void k_sim(const float* __restrict__ x, float* __restrict__ sim) {
  __shared__ float AT[32][132];                    // [k][row], +4 pad
  __shared__ float BT[32][140];                    // [k][w(col)], w(c)=c+4*(c>>5)
  const int bj = blockIdx.x;
  const int n0 = blockIdx.y * 128;
  const int m0 = blockIdx.z * 128;
  const int b = bj / JJ, jj = bj - b * JJ;
  const float* xb = x + ((size_t)b * TT * JJ + jj) * CC;   // + t*(JJ*CC) + k
  const int tid = threadIdx.x;
  const int tx = tid & 15, ty = tid >> 4;

  float acc[8][8];
  #pragma unroll
  for (int i = 0; i < 8; i++)
    #pragma unroll
    for (int q = 0; q < 8; q++) acc[i][q] = 0.f;

  for (int ks = 0; ks < CC; ks += 32) {
    #pragma unroll
    for (int it = 0; it < 4; ++it) {
      int s = tid + it * 256;                      // 1024 slots: 128 rows x 8 kq
      int kq = s & 7, r = s >> 3;
      {
        int t = n0 + r; if (t > TT - 1) t = TT - 1;
        float4 v = *reinterpret_cast<const float4*>(xb + (size_t)t * (JJ * CC) + ks + kq * 4);
        AT[kq * 4 + 0][r] = v.x; AT[kq * 4 + 1][r] = v.y;
        AT[kq * 4 + 2][r] = v.z; AT[kq * 4 + 3][r] = v.w;
      }
      {
        int t = m0 + r; if (t > TT - 1) t = TT - 1;
        float4 v = *reinterpret_cast<const float4*>(xb + (size_t)t * (JJ * CC) + ks + kq * 4);
        int pc = r + 4 * (r >> 5);
        BT[kq * 4 + 0][pc] = v.x; BT[kq * 4 + 1][pc] = v.y;
        BT[kq * 4 + 2][pc] = v.z; BT[kq * 4 + 3][pc] = v.w;
      }
    }
    __syncthreads();
    const int pa = ty * 8;
    const int pb = 8 * tx + 4 * (tx >> 2);         // w(8tx); w(8tx+4)=pb+4
    #pragma unroll 4
    for (int k = 0; k < 32; k++) {
      float4 a0 = *reinterpret_cast<const float4*>(&AT[k][pa]);
      float4 a1 = *reinterpret_cast<const float4*>(&AT[k][pa + 4]);
      float4 b0 = *reinterpret_cast<const float4*>(&BT[k][pb]);
      float4 b1 = *reinterpret_cast<const float4*>(&BT[k][pb + 4]);
      float av[8] = {a0.x, a0.y, a0.z, a0.w, a1.x, a1.y, a1.z, a1.w};
      float bv[8] = {b0.x, b0.y, b0.z, b0.w, b1.x, b1.y, b1.z, b1.w};
      #pragma unroll
      for (int i = 0; i < 8; i++)
        #pragma unroll
        for (int q = 0; q < 8; q++)
          acc[i][q] = __builtin_fmaf(av[i], bv[q], acc[i][q]);
    }
    __syncthreads();
  }

  const size_t base = (size_t)bj * TT * SIMP;
  const int c0 = m0 + tx * 8;
  #pragma unroll
  for (int i = 0; i < 8; i++) {
    int n = n0 + ty * 8 + i;
    if (n < TT) {
      if (c0 < TT)
        *reinterpret_cast<float4*>(sim + base + (size_t)n * SIMP + c0) =
          (float4){acc[i][0], acc[i][1], acc[i][2], acc[i][3]};
      if (c0 + 4 < TT)
        *reinterpret_cast<float4*>(sim + base + (size_t)n * SIMP + c0 + 4) =
          (float4){acc[i][4], acc[i][5], acc[i][6], acc[i][7]};
    }
  }
}

// ---------- K3a: per row: thr, dis, adjacency bitmask (4 waves = 4 rows/block) ----------
__launch_bounds__(256)
__global__ void k_topk(const float* __restrict__ sim,
                       float* __restrict__ dis_o,
                       unsigned long long* __restrict__ mask_o) {
  const int l = threadIdx.x & 63, wv = threadIdx.x >> 6;
  const int r = blockIdx.x * 4 + wv;               // MM % 4 == 0
  const float* row = sim + (size_t)r * SIMP;
  float o0 = (l       < TT) ? row[l]       : NEG_INF;
  float o1 = (l + 64  < TT) ? row[l + 64]  : NEG_INF;
  float o2 = (l + 128 < TT) ? row[l + 128] : NEG_INF;
  float o3 = (l + 192 < TT) ? row[l + 192] : NEG_INF;
  float v0 = o0, v1 = o1, v2 = o2, v3 = o3;
  { float mx, mn;
    mx=fmaxf(v0,v1); mn=fminf(v0,v1); v0=mx; v1=mn;
    mx=fmaxf(v2,v3); mn=fminf(v2,v3); v2=mx; v3=mn;
    mx=fmaxf(v0,v2); mn=fminf(v0,v2); v0=mx; v2=mn;
    mx=fmaxf(v1,v3); mn=fminf(v1,v3); v1=mx; v3=mn;
    mx=fmaxf(v1,v2); mn=fminf(v1,v2); v1=mx; v2=mn; }
  int p = 0;
  float thr = NEG_INF;
  #pragma unroll
  for (int it = 0; it < 4; ++it) {                 // extract one max instance per round
    float head = (p == 0) ? v0 : (p == 1) ? v1 : (p == 2) ? v2 : (p == 3) ? v3 : NEG_INF;
    float m = head;
    #pragma unroll
    for (int off = 1; off < 64; off <<= 1) m = fmaxf(m, __shfl_xor(m, off));
    thr = m;
    unsigned long long msk = __ballot(head == m);
    int first = __ffsll(msk) - 1;
    if (l == first) p++;
  }
  unsigned long long m0 = __ballot(o0 >= thr);
  unsigned long long m1 = __ballot(o1 >= thr);
  unsigned long long m2 = __ballot(o2 >= thr);
  unsigned long long m3 = __ballot(o3 >= thr);
  if (l == 0) {
    int deg = __popcll(m0) + __popcll(m1) + __popcll(m2) + __popcll(m3);
    dis_o[r] = rsqrtf((float)deg);
    mask_o[(size_t)r * 4 + 0] = m0;
    mask_o[(size_t)r * 4 + 1] = m1;
    mask_o[(size_t)r * 4 + 2] = m2;
    mask_o[(size_t)r * 4 + 3] = m3;
  }
}

// ---------- K3b: h = norm_adj @ v + u (one wave per row, 4 ch/lane) ----------
__launch_bounds__(512)
__global__ void k_agg(const unsigned long long* __restrict__ mask,
                      const float* __restrict__ dis, const unsigned short* __restrict__ u,
                      const unsigned short* __restrict__ v, unsigned short* __restrict__ h,
                      float* __restrict__ p1, float* __restrict__ p2) {
  __shared__ float dis_l[256];
  const int bj = blockIdx.x;
  const int tid = threadIdx.x, lane = tid & 63, wid = tid >> 6;
  if (tid < TT) dis_l[tid] = dis[(size_t)bj * TT + tid];
  __syncthreads();
  const int start = blockIdx.y * 122;
  const int cnt = blockIdx.y ? (TT - 122) : 122;
  const size_t pbase = (size_t)bj * TT;
  for (int rl = wid; rl < cnt; rl += 8) {
    const int t = start + rl;
    const size_t r = pbase + t;
    const float dr = dis_l[t];
    ushort4 uu = *reinterpret_cast<const ushort4*>(u + r * CC + lane * 4);
    float a0 = bf2f(uu.x), a1 = bf2f(uu.y), a2 = bf2f(uu.z), a3 = bf2f(uu.w);
    #pragma unroll
    for (int w4 = 0; w4 < 4; ++w4) {
      unsigned long long m = mask[r * 4 + w4];
      while (m) {
        int i = __ffsll(m) - 1;
        m &= m - 1;
        int idx = w4 * 64 + i;
        float w = dr * dis_l[idx];
        ushort4 vv = *reinterpret_cast<const ushort4*>(v + (pbase + idx) * CC + lane * 4);
        a0 = __builtin_fmaf(w, bf2f(vv.x), a0);
        a1 = __builtin_fmaf(w, bf2f(vv.y), a1);
        a2 = __builtin_fmaf(w, bf2f(vv.z), a2);
        a3 = __builtin_fmaf(w, bf2f(vv.w), a3);
      }
    }
    ushort4 hh;
    hh.x = f2bf(a0); hh.y = f2bf(a1); hh.z = f2bf(a2); hh.w = f2bf(a3);
    *reinterpret_cast<ushort4*>(h + r * CC + lane * 4) = hh;
    float s1 = a0 + a1 + a2 + a3;
    float s2 = a0*a0 + a1*a1 + a2*a2 + a3*a3;
    #pragma unroll
    for (int off = 1; off < 64; off <<= 1) { s1 += __shfl_xor(s1, off); s2 += __shfl_xor(s2, off); }
    if (lane == 0) { p1[r] = s1; p2[r] = s2; }
  }
}

// ---------- K4: BN stats per t -> scale/shift ----------
__global__ void k_bnstat(const float* __restrict__ p1, const float* __restrict__ p2,
                         const float* __restrict__ gamma, const float* __restrict__ beta,
                         float* __restrict__ scale, float* __restrict__ shift) {
  __shared__ float sA[256], sB[256];
  const int t = blockIdx.x;                        // 0..TT-1
  const int tid = threadIdx.x;
  float a = 0.f, b2 = 0.f;
  for (int bj = tid; bj < BJC; bj += 256) {
    a  += p1[bj * TT + t];
    b2 += p2[bj * TT + t];
  }
  sA[tid] = a; sB[tid] = b2;
  __syncthreads();
  for (int s = 128; s > 0; s >>= 1) {
    if (tid < s) { sA[tid] += sA[tid + s]; sB[tid] += sB[tid + s]; }
    __syncthreads();
  }
  if (tid == 0) {
    const float invN = 1.0f / (float)(BJC * CC);
    float mean = sA[0] * invN;
    float var  = sB[0] * invN - mean * mean;
    float sc   = rsqrtf(var + 1e-5f) * gamma[t];
    scale[t] = sc;
    shift[t] = beta[t] - mean * sc;
  }
}

// ---------- K5: out = relu(x + h*scale + shift), back to [B,T,J,C] ----------
__global__ void k_out(const float* __restrict__ x, const unsigned short* __restrict__ h,
                      const float* __restrict__ scale, const float* __restrict__ shift,
                      float* __restrict__ out) {
  int g = blockIdx.x * 256 + threadIdx.x;
  if (g >= MM * (CC/4)) return;
  int c4  = g & 63;
  int rowx = g >> 6;                               // (b*TT + t)*JJ + j
  int b   = rowx / (TT*JJ);
  int rem = rowx - b*(TT*JJ);
  int t   = rem / JJ;
  int j   = rem - t*JJ;
  size_t hoff = ((size_t)(b*JJ + j) * TT + t) * CC + c4*4;
  float4 xv = *reinterpret_cast<const float4*>(x + (size_t)rowx*CC + c4*4);
  ushort4 hv = *reinterpret_cast<const ushort4*>(h + hoff);
  float sc = scale[t], sh = shift[t];
  float4 o;
  o.x = fmaxf(xv.x + bf2f(hv.x)*sc + sh, 0.f);
  o.y = fmaxf(xv.y + bf2f(hv.y)*sc + sh, 0.f);
  o.z = fmaxf(xv.z + bf2f(hv.z)*sc + sh, 0.f);
  o.w = fmaxf(xv.w + bf2f(hv.w)*sc + sh, 0.f);
  *reinterpret_cast<float4*>(out + (size_t)rowx*CC + c4*4) = o;
}

extern "C" void kernel_launch(void* const* d_in, const int* in_sizes, int n_in,
                              void* d_out, int out_size, void* d_ws, size_t ws_size,
                              hipStream_t stream) {
  const float* x     = (const float*)d_in[0];
  const float* Wu    = (const float*)d_in[1];
  const float* bu    = (const float*)d_in[2];
  const float* Wv    = (const float*)d_in[3];
  const float* bv    = (const float*)d_in[4];
  const float* gamma = (const float*)d_in[5];
  const float* beta  = (const float*)d_in[6];
  float* out = (float*)d_out;

  char* ws = (char*)d_ws;
  size_t off = 0;
  auto alloc = [&](size_t bytes) -> void* {
    void* p = ws + off;
    off = (off + bytes + 255) & ~(size_t)255;
    return p;
  };
  unsigned short* u   = (unsigned short*)alloc((size_t)MM * CC * 2);
  unsigned short* v   = (unsigned short*)alloc((size_t)MM * CC * 2);
  unsigned short* h   = (unsigned short*)alloc((size_t)MM * CC * 2);
  unsigned short* wc  = (unsigned short*)alloc((size_t)512 * CC * 2);
  float* sim = (float*)alloc((size_t)BJC * TT * SIMP * 4);
  float* dis = (float*)alloc((size_t)MM * 4);
  unsigned long long* msk = (unsigned long long*)alloc((size_t)MM * 4 * 8);
  float* p1    = (float*)alloc((size_t)MM * 4);
  float* p2    = (float*)alloc((size_t)MM * 4);
  float* scale = (float*)alloc(1024);
  float* shift = (float*)alloc(1024);

  if (ws_size < off) {                             // clean failure signal, no OOB
    hipMemsetAsync(d_out, 0, (size_t)out_size * 4, stream);
    return;
  }

  k_prep_w<<<dim3((512*(CC/4) + 255)/256), dim3(256), 0, stream>>>(Wu, Wv, wc);
  k_uv   <<<dim3((MM + 127)/128, 4), dim3(256), 0, stream>>>(x, wc, bu, bv, u, v);
  k_sim  <<<dim3(BJC, 2, 2), dim3(256), 0, stream>>>(x, sim);
  k_topk <<<dim3(MM/4), dim3(256), 0, stream>>>(sim, dis, msk);
  k_agg  <<<dim3(BJC, 2), dim3(512), 0, stream>>>(msk, dis, u, v, h, p1, p2);
  k_bnstat<<<dim3(TT), dim3(256), 0, stream>>>(p1, p2, gamma, beta, scale, shift);
  k_out  <<<dim3((MM*(CC/4) + 255)/256), dim3(256), 0, stream>>>(x, h, scale, shift, out);
}

// Round 3
// 560.244 us; speedup vs baseline: 1.2970x; 1.0291x over previous
//
#include <hip/hip_runtime.h>

#define BB 32
#define TT 243
#define JJ 17
#define CC 256
#define BJC (BB*JJ)          // 544
#define MM (BJC*TT)          // 132192 rows (bj-major: r = bj*TT + t)
#define SIMP 244             // padded sim row stride (16B-aligned rows)
#define NEG_INF (-3.0e38f)

typedef __attribute__((ext_vector_type(8))) short bf16x8;
typedef __attribute__((ext_vector_type(4))) float f32x4;

__device__ __forceinline__ unsigned short f2bf(float f) {
  unsigned int u = __float_as_uint(f);
  u = (u + 0x7fffu + ((u >> 16) & 1u)) >> 16;   // RNE
  return (unsigned short)u;
}
__device__ __forceinline__ float bf2f(unsigned short s) {
  return __uint_as_float(((unsigned int)s) << 16);
}

// ---------- K0b: W_u,W_v f32 [C,C] -> wc bf16 [512,C] ----------
__global__ void k_prep_w(const float* __restrict__ Wu, const float* __restrict__ Wv,
                         unsigned short* __restrict__ wc) {
  int g = blockIdx.x * 256 + threadIdx.x;
  if (g >= 512 * (CC/4)) return;
  int c4 = g & 63;
  int n  = g >> 6;
  const float* src = (n < CC) ? (Wu + (size_t)n*CC) : (Wv + (size_t)(n-CC)*CC);
  float4 v = *reinterpret_cast<const float4*>(src + c4*4);
  ushort4 o;
  o.x = f2bf(v.x); o.y = f2bf(v.y); o.z = f2bf(v.z); o.w = f2bf(v.w);
  *reinterpret_cast<ushort4*>(wc + (size_t)n*CC + c4*4) = o;
}

// ---------- K1: u,v = x @ W^T + b  (bf16 MFMA, A converted from f32 on the fly) ----------
__launch_bounds__(256)
__global__ void k_uv(const float* __restrict__ x,
                     const unsigned short* __restrict__ wc,
                     const float* __restrict__ bu, const float* __restrict__ bv,
                     unsigned short* __restrict__ uo, unsigned short* __restrict__ vo) {
  __shared__ unsigned short Al[128][40];   // +8 pad
  __shared__ unsigned short Bl[128][40];
  const int tid  = threadIdx.x;
  const int lane = tid & 63, wid = tid >> 6;
  const int wm = (wid >> 1) * 64, wn = (wid & 1) * 64;
  const int m0 = blockIdx.x * 128, n0 = blockIdx.y * 128;

  const int kq8 = tid & 7;
  size_t arow[4];
  int r_it[4];
  #pragma unroll
  for (int it = 0; it < 4; ++it) {
    int r = (tid >> 3) + it * 32;
    r_it[it] = r;
    int gm = m0 + r; if (gm > MM - 1) gm = MM - 1;
    int bj = gm / TT, t = gm - bj * TT;
    int b = bj / JJ, j = bj - b * JJ;
    arow[it] = ((size_t)(b * TT + t) * JJ + j) * CC;
  }

  f32x4 acc[4][4];
  #pragma unroll
  for (int i = 0; i < 4; i++)
    #pragma unroll
    for (int j = 0; j < 4; j++) acc[i][j] = (f32x4){0.f, 0.f, 0.f, 0.f};

  for (int ks = 0; ks < CC; ks += 32) {
    #pragma unroll
    for (int it = 0; it < 4; ++it) {
      float4 xv = *reinterpret_cast<const float4*>(x + arow[it] + ks + kq8 * 4);
      ushort4 o;
      o.x = f2bf(xv.x); o.y = f2bf(xv.y); o.z = f2bf(xv.z); o.w = f2bf(xv.w);
      *reinterpret_cast<ushort4*>(&Al[r_it[it]][kq8 * 4]) = o;
    }
    #pragma unroll
    for (int it = 0; it < 2; ++it) {
      int s = tid + it * 256;
      int r = s >> 2, kq = s & 3;
      *reinterpret_cast<uint4*>(&Bl[r][kq * 8]) =
        *reinterpret_cast<const uint4*>(wc + (size_t)(n0 + r) * CC + ks + kq * 8);
    }
    __syncthreads();
    const int kf = (lane >> 4) * 8;
    bf16x8 af[4], bfv[4];
    #pragma unroll
    for (int i = 0; i < 4; i++)
      af[i] = *reinterpret_cast<const bf16x8*>(&Al[wm + i * 16 + (lane & 15)][kf]);
    #pragma unroll
    for (int j = 0; j < 4; j++)
      bfv[j] = *reinterpret_cast<const bf16x8*>(&Bl[wn + j * 16 + (lane & 15)][kf]);
    #pragma unroll
    for (int i = 0; i < 4; i++)
      #pragma unroll
      for (int j = 0; j < 4; j++)
        acc[i][j] = __builtin_amdgcn_mfma_f32_16x16x32_bf16(af[i], bfv[j], acc[i][j], 0, 0, 0);
    __syncthreads();
  }

  float bias[4];
  #pragma unroll
  for (int j = 0; j < 4; j++) {
    int gn = n0 + wn + j * 16 + (lane & 15);
    bias[j] = (gn < CC) ? bu[gn] : bv[gn - CC];
  }
  const int rq = (lane >> 4) * 4;
  #pragma unroll
  for (int i = 0; i < 4; i++) {
    #pragma unroll
    for (int q = 0; q < 4; q++) {
      int gm = m0 + wm + i * 16 + rq + q;
      if (gm < MM) {
        #pragma unroll
        for (int j = 0; j < 4; j++) {
          int gn = n0 + wn + j * 16 + (lane & 15);
          float val = acc[i][j][q] + bias[j];
          if (gn < CC) uo[(size_t)gm * CC + gn] = f2bf(val);
          else         vo[(size_t)gm * CC + gn - CC] = f2bf(val);
        }
      }
    }
  }
}

// ---------- K2: sim = xr @ xr^T per bj (symmetric: 3 of 4 tiles), fp32 VALU ----------
// 128 threads, 16x8 per-thread register tile, conflict-free LDS layouts.
// tz=0: (0,0) diag; tz=1: (128,128) diag; tz=2: (128,0) + mirrored write.
__launch_bounds__(128)
__global__ void k_sim(const float* __restrict__ x, float* __restrict__ sim) {
  __shared__ float AT[32][144];   // [k][p(r)], p(r)=r+4*(r>>5)
  __shared__ float BT[32][136];   // [k][q(c)], q(c)=c+2*(c>>5)
  const int tz = blockIdx.x;
  const int bj = blockIdx.y;
  const int r0 = tz ? 128 : 0;
  const int c0 = (tz == 1) ? 128 : 0;
  const int b = bj / JJ, jj = bj - b * JJ;
  const float* xb = x + ((size_t)b * TT * JJ + jj) * CC;   // + t*(JJ*CC) + k
  const int tid = threadIdx.x;
  const int tx = tid & 15, ty = tid >> 4;                  // 16 x 8 thread grid

  int ra = r0 + tid; if (ra > TT - 1) ra = TT - 1;
  int rb = c0 + tid; if (rb > TT - 1) rb = TT - 1;
  const float* ga = xb + (size_t)ra * (JJ * CC);
  const float* gb = xb + (size_t)rb * (JJ * CC);
  const int pst = tid + 4 * (tid >> 5);                    // AT store pos (bank-perm)
  const int qst = tid + 2 * (tid >> 5);                    // BT store pos (bank-perm)
  const int pa = ty * 16 + 4 * (ty >> 1);                  // p(ty*16)
  const int qb = tx * 8 + 2 * (tx >> 2);                   // q(tx*8)

  float acc[16][8];
  #pragma unroll
  for (int i = 0; i < 16; i++)
    #pragma unroll
    for (int q = 0; q < 8; q++) acc[i][q] = 0.f;

  for (int ks = 0; ks < CC; ks += 32) {
    #pragma unroll
    for (int it = 0; it < 8; ++it) {
      float4 va = *reinterpret_cast<const float4*>(ga + ks + it * 4);
      AT[it*4+0][pst] = va.x; AT[it*4+1][pst] = va.y;
      AT[it*4+2][pst] = va.z; AT[it*4+3][pst] = va.w;
      float4 vb = *reinterpret_cast<const float4*>(gb + ks + it * 4);
      BT[it*4+0][qst] = vb.x; BT[it*4+1][qst] = vb.y;
      BT[it*4+2][qst] = vb.z; BT[it*4+3][qst] = vb.w;
    }
    __syncthreads();
    #pragma unroll 4
    for (int kk = 0; kk < 32; ++kk) {
      float a_[16], b_[8];
      *reinterpret_cast<float4*>(&a_[0])  = *reinterpret_cast<const float4*>(&AT[kk][pa]);
      *reinterpret_cast<float4*>(&a_[4])  = *reinterpret_cast<const float4*>(&AT[kk][pa + 4]);
      *reinterpret_cast<float4*>(&a_[8])  = *reinterpret_cast<const float4*>(&AT[kk][pa + 8]);
      *reinterpret_cast<float4*>(&a_[12]) = *reinterpret_cast<const float4*>(&AT[kk][pa + 12]);
      *reinterpret_cast<float2*>(&b_[0])  = *reinterpret_cast<const float2*>(&BT[kk][qb]);
      *reinterpret_cast<float2*>(&b_[2])  = *reinterpret_cast<const float2*>(&BT[kk][qb + 2]);
      *reinterpret_cast<float2*>(&b_[4])  = *reinterpret_cast<const float2*>(&BT[kk][qb + 4]);
      *reinterpret_cast<float2*>(&b_[6])  = *reinterpret_cast<const float2*>(&BT[kk][qb + 6]);
      #pragma unroll
      for (int i = 0; i < 16; i++)
        #pragma unroll
        for (int q = 0; q < 8; q++)
          acc[i][q] = __builtin_fmaf(a_[i], b_[q], acc[i][q]);
    }
    __syncthreads();
  }

  const size_t base = (size_t)bj * TT * SIMP;
  const int c = c0 + tx * 8;
  #pragma unroll
  for (int i = 0; i < 16; ++i) {
    int n = r0 + ty * 16 + i;
    if (n < TT) {
      if (c + 7 < TT) {
        *reinterpret_cast<float4*>(sim + base + (size_t)n * SIMP + c) =
          (float4){acc[i][0], acc[i][1], acc[i][2], acc[i][3]};
        *reinterpret_cast<float4*>(sim + base + (size_t)n * SIMP + c + 4) =
          (float4){acc[i][4], acc[i][5], acc[i][6], acc[i][7]};
      } else {
        #pragma unroll
        for (int q = 0; q < 8; q++)
          if (c + q < TT) sim[base + (size_t)n * SIMP + c + q] = acc[i][q];
      }
    }
  }
  if (tz == 2) {                                           // mirror: sim[c][n] = acc
    #pragma unroll
    for (int q = 0; q < 8; ++q) {
      const size_t mb = base + (size_t)(c + q) * SIMP;     // c+q < 128 always valid
      #pragma unroll
      for (int g = 0; g < 4; ++g) {
        int n0 = r0 + ty * 16 + g * 4;
        if (n0 + 3 < TT) {
          *reinterpret_cast<float4*>(sim + mb + n0) =
            (float4){acc[g*4+0][q], acc[g*4+1][q], acc[g*4+2][q], acc[g*4+3][q]};
        } else {
          #pragma unroll
          for (int e = 0; e < 4; e++)
            if (n0 + e < TT) sim[mb + n0 + e] = acc[g*4+e][q];
        }
      }
    }
  }
}

// ---------- K3a: per row: thr, dis, adjacency bitmask (4 waves = 4 rows/block) ----------
__launch_bounds__(256)
__global__ void k_topk(const float* __restrict__ sim,
                       float* __restrict__ dis_o,
                       unsigned long long* __restrict__ mask_o) {
  const int l = threadIdx.x & 63, wv = threadIdx.x >> 6;
  const int r = blockIdx.x * 4 + wv;               // MM % 4 == 0
  const float* row = sim + (size_t)r * SIMP;
  float o0 = (l       < TT) ? row[l]       : NEG_INF;
  float o1 = (l + 64  < TT) ? row[l + 64]  : NEG_INF;
  float o2 = (l + 128 < TT) ? row[l + 128] : NEG_INF;
  float o3 = (l + 192 < TT) ? row[l + 192] : NEG_INF;
  float v0 = o0, v1 = o1, v2 = o2, v3 = o3;
  { float mx, mn;
    mx=fmaxf(v0,v1); mn=fminf(v0,v1); v0=mx; v1=mn;
    mx=fmaxf(v2,v3); mn=fminf(v2,v3); v2=mx; v3=mn;
    mx=fmaxf(v0,v2); mn=fminf(v0,v2); v0=mx; v2=mn;
    mx=fmaxf(v1,v3); mn=fminf(v1,v3); v1=mx; v3=mn;
    mx=fmaxf(v1,v2); mn=fminf(v1,v2); v1=mx; v2=mn; }
  int p = 0;
  float thr = NEG_INF;
  #pragma unroll
  for (int it = 0; it < 4; ++it) {
    float head = (p == 0) ? v0 : (p == 1) ? v1 : (p == 2) ? v2 : (p == 3) ? v3 : NEG_INF;
    float m = head;
    #pragma unroll
    for (int off = 1; off < 64; off <<= 1) m = fmaxf(m, __shfl_xor(m, off));
    thr = m;
    unsigned long long msk = __ballot(head == m);
    int first = __ffsll(msk) - 1;
    if (l == first) p++;
  }
  unsigned long long m0 = __ballot(o0 >= thr);
  unsigned long long m1 = __ballot(o1 >= thr);
  unsigned long long m2 = __ballot(o2 >= thr);
  unsigned long long m3 = __ballot(o3 >= thr);
  if (l == 0) {
    int deg = __popcll(m0) + __popcll(m1) + __popcll(m2) + __popcll(m3);
    dis_o[r] = rsqrtf((float)deg);
    mask_o[(size_t)r * 4 + 0] = m0;
    mask_o[(size_t)r * 4 + 1] = m1;
    mask_o[(size_t)r * 4 + 2] = m2;
    mask_o[(size_t)r * 4 + 3] = m3;
  }
}

// ---------- K3b: h = norm_adj @ v + u (one wave per row, 4 ch/lane) ----------
__launch_bounds__(512)
__global__ void k_agg(const unsigned long long* __restrict__ mask,
                      const float* __restrict__ dis, const unsigned short* __restrict__ u,
                      const unsigned short* __restrict__ v, unsigned short* __restrict__ h,
                      float* __restrict__ p1, float* __restrict__ p2) {
  __shared__ float dis_l[256];
  const int bj = blockIdx.x;
  const int tid = threadIdx.x, lane = tid & 63, wid = tid >> 6;
  if (tid < TT) dis_l[tid] = dis[(size_t)bj * TT + tid];
  __syncthreads();
  const int start = blockIdx.y * 122;
  const int cnt = blockIdx.y ? (TT - 122) : 122;
  const size_t pbase = (size_t)bj * TT;
  for (int rl = wid; rl < cnt; rl += 8) {
    const int t = start + rl;
    const size_t r = pbase + t;
    const float dr = dis_l[t];
    ushort4 uu = *reinterpret_cast<const ushort4*>(u + r * CC + lane * 4);
    float a0 = bf2f(uu.x), a1 = bf2f(uu.y), a2 = bf2f(uu.z), a3 = bf2f(uu.w);
    #pragma unroll
    for (int w4 = 0; w4 < 4; ++w4) {
      unsigned long long m = mask[r * 4 + w4];
      while (m) {
        int i = __ffsll(m) - 1;
        m &= m - 1;
        int idx = w4 * 64 + i;
        float w = dr * dis_l[idx];
        ushort4 vv = *reinterpret_cast<const ushort4*>(v + (pbase + idx) * CC + lane * 4);
        a0 = __builtin_fmaf(w, bf2f(vv.x), a0);
        a1 = __builtin_fmaf(w, bf2f(vv.y), a1);
        a2 = __builtin_fmaf(w, bf2f(vv.z), a2);
        a3 = __builtin_fmaf(w, bf2f(vv.w), a3);
      }
    }
    ushort4 hh;
    hh.x = f2bf(a0); hh.y = f2bf(a1); hh.z = f2bf(a2); hh.w = f2bf(a3);
    *reinterpret_cast<ushort4*>(h + r * CC + lane * 4) = hh;
    float s1 = a0 + a1 + a2 + a3;
    float s2 = a0*a0 + a1*a1 + a2*a2 + a3*a3;
    #pragma unroll
    for (int off = 1; off < 64; off <<= 1) { s1 += __shfl_xor(s1, off); s2 += __shfl_xor(s2, off); }
    if (lane == 0) { p1[r] = s1; p2[r] = s2; }
  }
}

// ---------- K4: BN stats per t -> scale/shift ----------
__global__ void k_bnstat(const float* __restrict__ p1, const float* __restrict__ p2,
                         const float* __restrict__ gamma, const float* __restrict__ beta,
                         float* __restrict__ scale, float* __restrict__ shift) {
  __shared__ float sA[256], sB[256];
  const int t = blockIdx.x;
  const int tid = threadIdx.x;
  float a = 0.f, b2 = 0.f;
  for (int bj = tid; bj < BJC; bj += 256) {
    a  += p1[bj * TT + t];
    b2 += p2[bj * TT + t];
  }
  sA[tid] = a; sB[tid] = b2;
  __syncthreads();
  for (int s = 128; s > 0; s >>= 1) {
    if (tid < s) { sA[tid] += sA[tid + s]; sB[tid] += sB[tid + s]; }
    __syncthreads();
  }
  if (tid == 0) {
    const float invN = 1.0f / (float)(BJC * CC);
    float mean = sA[0] * invN;
    float var  = sB[0] * invN - mean * mean;
    float sc   = rsqrtf(var + 1e-5f) * gamma[t];
    scale[t] = sc;
    shift[t] = beta[t] - mean * sc;
  }
}

// ---------- K5: out = relu(x + h*scale + shift), back to [B,T,J,C] ----------
__global__ void k_out(const float* __restrict__ x, const unsigned short* __restrict__ h,
                      const float* __restrict__ scale, const float* __restrict__ shift,
                      float* __restrict__ out) {
  int g = blockIdx.x * 256 + threadIdx.x;
  if (g >= MM * (CC/4)) return;
  int c4  = g & 63;
  int rowx = g >> 6;
  int b   = rowx / (TT*JJ);
  int rem = rowx - b*(TT*JJ);
  int t   = rem / JJ;
  int j   = rem - t*JJ;
  size_t hoff = ((size_t)(b*JJ + j) * TT + t) * CC + c4*4;
  float4 xv = *reinterpret_cast<const float4*>(x + (size_t)rowx*CC + c4*4);
  ushort4 hv = *reinterpret_cast<const ushort4*>(h + hoff);
  float sc = scale[t], sh = shift[t];
  float4 o;
  o.x = fmaxf(xv.x + bf2f(hv.x)*sc + sh, 0.f);
  o.y = fmaxf(xv.y + bf2f(hv.y)*sc + sh, 0.f);
  o.z = fmaxf(xv.z + bf2f(hv.z)*sc + sh, 0.f);
  o.w = fmaxf(xv.w + bf2f(hv.w)*sc + sh, 0.f);
  *reinterpret_cast<float4*>(out + (size_t)rowx*CC + c4*4) = o;
}

extern "C" void kernel_launch(void* const* d_in, const int* in_sizes, int n_in,
                              void* d_out, int out_size, void* d_ws, size_t ws_size,
                              hipStream_t stream) {
  const float* x     = (const float*)d_in[0];
  const float* Wu    = (const float*)d_in[1];
  const float* bu    = (const float*)d_in[2];
  const float* Wv    = (const float*)d_in[3];
  const float* bv    = (const float*)d_in[4];
  const float* gamma = (const float*)d_in[5];
  const float* beta  = (const float*)d_in[6];
  float* out = (float*)d_out;

  char* ws = (char*)d_ws;
  size_t off = 0;
  auto alloc = [&](size_t bytes) -> void* {
    void* p = ws + off;
    off = (off + bytes + 255) & ~(size_t)255;
    return p;
  };
  unsigned short* u   = (unsigned short*)alloc((size_t)MM * CC * 2);
  unsigned short* v   = (unsigned short*)alloc((size_t)MM * CC * 2);
  unsigned short* h   = (unsigned short*)alloc((size_t)MM * CC * 2);
  unsigned short* wc  = (unsigned short*)alloc((size_t)512 * CC * 2);
  float* sim = (float*)alloc((size_t)BJC * TT * SIMP * 4);
  float* dis = (float*)alloc((size_t)MM * 4);
  unsigned long long* msk = (unsigned long long*)alloc((size_t)MM * 4 * 8);
  float* p1    = (float*)alloc((size_t)MM * 4);
  float* p2    = (float*)alloc((size_t)MM * 4);
  float* scale = (float*)alloc(1024);
  float* shift = (float*)alloc(1024);

  if (ws_size < off) {
    hipMemsetAsync(d_out, 0, (size_t)out_size * 4, stream);
    return;
  }

  k_prep_w<<<dim3((512*(CC/4) + 255)/256), dim3(256), 0, stream>>>(Wu, Wv, wc);
  k_uv   <<<dim3((MM + 127)/128, 4), dim3(256), 0, stream>>>(x, wc, bu, bv, u, v);
  k_sim  <<<dim3(3, BJC), dim3(128), 0, stream>>>(x, sim);
  k_topk <<<dim3(MM/4), dim3(256), 0, stream>>>(sim, dis, msk);
  k_agg  <<<dim3(BJC, 2), dim3(512), 0, stream>>>(msk, dis, u, v, h, p1, p2);
  k_bnstat<<<dim3(TT), dim3(256), 0, stream>>>(p1, p2, gamma, beta, scale, shift);
  k_out  <<<dim3((MM*(CC/4) + 255)/256), dim3(256), 0, stream>>>(x, h, scale, shift, out);
}

// Round 4
// 444.967 us; speedup vs baseline: 1.6330x; 1.2591x over previous
//
#include <hip/hip_runtime.h>

#define BB 32
#define TT 243
#define JJ 17
#define CC 256
#define BJC (BB*JJ)          // 544
#define MM (BJC*TT)          // 132192 rows (bj-major: r = bj*TT + t)
#define SIMP 244             // padded sim row stride (16B-aligned rows)
#define NEG_INF (-3.0e38f)

typedef __attribute__((ext_vector_type(8))) short bf16x8;
typedef __attribute__((ext_vector_type(4))) float f32x4;
typedef __attribute__((ext_vector_type(8))) _Float16 f16x8;
typedef __attribute__((ext_vector_type(4))) _Float16 f16x4;

__device__ __forceinline__ unsigned short f2bf(float f) {
  unsigned int u = __float_as_uint(f);
  u = (u + 0x7fffu + ((u >> 16) & 1u)) >> 16;   // RNE
  return (unsigned short)u;
}
__device__ __forceinline__ float bf2f(unsigned short s) {
  return __uint_as_float(((unsigned int)s) << 16);
}

// ---------- K0b: W_u,W_v f32 [C,C] -> wc bf16 [512,C] ----------
__global__ void k_prep_w(const float* __restrict__ Wu, const float* __restrict__ Wv,
                         unsigned short* __restrict__ wc) {
  int g = blockIdx.x * 256 + threadIdx.x;
  if (g >= 512 * (CC/4)) return;
  int c4 = g & 63;
  int n  = g >> 6;
  const float* src = (n < CC) ? (Wu + (size_t)n*CC) : (Wv + (size_t)(n-CC)*CC);
  float4 v = *reinterpret_cast<const float4*>(src + c4*4);
  ushort4 o;
  o.x = f2bf(v.x); o.y = f2bf(v.y); o.z = f2bf(v.z); o.w = f2bf(v.w);
  *reinterpret_cast<ushort4*>(wc + (size_t)n*CC + c4*4) = o;
}

// ---------- K1: u,v = x @ W^T + b  (bf16 MFMA, A converted from f32 on the fly) ----------
__launch_bounds__(256)
__global__ void k_uv(const float* __restrict__ x,
                     const unsigned short* __restrict__ wc,
                     const float* __restrict__ bu, const float* __restrict__ bv,
                     unsigned short* __restrict__ uo, unsigned short* __restrict__ vo) {
  __shared__ unsigned short Al[128][40];   // +8 pad
  __shared__ unsigned short Bl[128][40];
  const int tid  = threadIdx.x;
  const int lane = tid & 63, wid = tid >> 6;
  const int wm = (wid >> 1) * 64, wn = (wid & 1) * 64;
  const int m0 = blockIdx.x * 128, n0 = blockIdx.y * 128;

  const int kq8 = tid & 7;
  size_t arow[4];
  int r_it[4];
  #pragma unroll
  for (int it = 0; it < 4; ++it) {
    int r = (tid >> 3) + it * 32;
    r_it[it] = r;
    int gm = m0 + r; if (gm > MM - 1) gm = MM - 1;
    int bj = gm / TT, t = gm - bj * TT;
    int b = bj / JJ, j = bj - b * JJ;
    arow[it] = ((size_t)(b * TT + t) * JJ + j) * CC;
  }

  f32x4 acc[4][4];
  #pragma unroll
  for (int i = 0; i < 4; i++)
    #pragma unroll
    for (int j = 0; j < 4; j++) acc[i][j] = (f32x4){0.f, 0.f, 0.f, 0.f};

  for (int ks = 0; ks < CC; ks += 32) {
    #pragma unroll
    for (int it = 0; it < 4; ++it) {
      float4 xv = *reinterpret_cast<const float4*>(x + arow[it] + ks + kq8 * 4);
      ushort4 o;
      o.x = f2bf(xv.x); o.y = f2bf(xv.y); o.z = f2bf(xv.z); o.w = f2bf(xv.w);
      *reinterpret_cast<ushort4*>(&Al[r_it[it]][kq8 * 4]) = o;
    }
    #pragma unroll
    for (int it = 0; it < 2; ++it) {
      int s = tid + it * 256;
      int r = s >> 2, kq = s & 3;
      *reinterpret_cast<uint4*>(&Bl[r][kq * 8]) =
        *reinterpret_cast<const uint4*>(wc + (size_t)(n0 + r) * CC + ks + kq * 8);
    }
    __syncthreads();
    const int kf = (lane >> 4) * 8;
    bf16x8 af[4], bfv[4];
    #pragma unroll
    for (int i = 0; i < 4; i++)
      af[i] = *reinterpret_cast<const bf16x8*>(&Al[wm + i * 16 + (lane & 15)][kf]);
    #pragma unroll
    for (int j = 0; j < 4; j++)
      bfv[j] = *reinterpret_cast<const bf16x8*>(&Bl[wn + j * 16 + (lane & 15)][kf]);
    #pragma unroll
    for (int i = 0; i < 4; i++)
      #pragma unroll
      for (int j = 0; j < 4; j++)
        acc[i][j] = __builtin_amdgcn_mfma_f32_16x16x32_bf16(af[i], bfv[j], acc[i][j], 0, 0, 0);
    __syncthreads();
  }

  float bias[4];
  #pragma unroll
  for (int j = 0; j < 4; j++) {
    int gn = n0 + wn + j * 16 + (lane & 15);
    bias[j] = (gn < CC) ? bu[gn] : bv[gn - CC];
  }
  const int rq = (lane >> 4) * 4;
  #pragma unroll
  for (int i = 0; i < 4; i++) {
    #pragma unroll
    for (int q = 0; q < 4; q++) {
      int gm = m0 + wm + i * 16 + rq + q;
      if (gm < MM) {
        #pragma unroll
        for (int j = 0; j < 4; j++) {
          int gn = n0 + wn + j * 16 + (lane & 15);
          float val = acc[i][j][q] + bias[j];
          if (gn < CC) uo[(size_t)gm * CC + gn] = f2bf(val);
          else         vo[(size_t)gm * CC + gn - CC] = f2bf(val);
        }
      }
    }
  }
}

// ---------- K2: sim = xr @ xr^T per bj via split-fp16 MFMA (3 passes) ----------
// x = hi + lo (hi=f16(x), lo=f16(x-hi)); sim ≈ A_hi B_hi + A_hi B_lo + A_lo B_hi.
// Dropped lo*lo + split residue ~ 3*2^-22|xy| per product -> below fp32 accum noise.
// 128x128 tile, 4 waves, k_uv fragment geometry (empirically verified).
__launch_bounds__(256)
__global__ void k_sim(const float* __restrict__ x, float* __restrict__ sim) {
  __shared__ _Float16 Ah[128][40];   // +8 pad halves (16B)
  __shared__ _Float16 Al[128][40];
  __shared__ _Float16 Bh[128][40];
  __shared__ _Float16 Bl[128][40];
  const int tile = blockIdx.x;                 // 0..3: mt = tile>>1, nt = tile&1
  const int bj = blockIdx.y;
  const int m0 = (tile >> 1) * 128, n0 = (tile & 1) * 128;
  const int b = bj / JJ, jj = bj - b * JJ;
  const float* xb = x + ((size_t)b * TT * JJ + jj) * CC;   // + t*(JJ*CC) + k
  const int tid = threadIdx.x;
  const int lane = tid & 63, wid = tid >> 6;
  const int wm = (wid >> 1) * 64, wn = (wid & 1) * 64;

  // staging slots: s = tid + it*256 over 1024 = 128 rows x 8 quads(4k each)
  const int kq = tid & 7;
  int ra[4], rb[4];
  const float *gpa[4], *gpb[4];
  #pragma unroll
  for (int it = 0; it < 4; ++it) {
    int r = (tid >> 3) + it * 32;
    ra[it] = r; rb[it] = r;
    int ta = m0 + r; if (ta > TT - 1) ta = TT - 1;
    int tb = n0 + r; if (tb > TT - 1) tb = TT - 1;
    gpa[it] = xb + (size_t)ta * (JJ * CC);
    gpb[it] = xb + (size_t)tb * (JJ * CC);
  }

  f32x4 acc[4][4];
  #pragma unroll
  for (int i = 0; i < 4; i++)
    #pragma unroll
    for (int j = 0; j < 4; j++) acc[i][j] = (f32x4){0.f, 0.f, 0.f, 0.f};

  for (int ks = 0; ks < CC; ks += 32) {
    #pragma unroll
    for (int it = 0; it < 4; ++it) {
      float4 va = *reinterpret_cast<const float4*>(gpa[it] + ks + kq * 4);
      _Float16 h0 = (_Float16)va.x, h1 = (_Float16)va.y,
               h2 = (_Float16)va.z, h3 = (_Float16)va.w;
      f16x4 hv = (f16x4){h0, h1, h2, h3};
      f16x4 lv = (f16x4){(_Float16)(va.x - (float)h0), (_Float16)(va.y - (float)h1),
                         (_Float16)(va.z - (float)h2), (_Float16)(va.w - (float)h3)};
      *reinterpret_cast<f16x4*>(&Ah[ra[it]][kq * 4]) = hv;
      *reinterpret_cast<f16x4*>(&Al[ra[it]][kq * 4]) = lv;
      float4 vb = *reinterpret_cast<const float4*>(gpb[it] + ks + kq * 4);
      h0 = (_Float16)vb.x; h1 = (_Float16)vb.y; h2 = (_Float16)vb.z; h3 = (_Float16)vb.w;
      hv = (f16x4){h0, h1, h2, h3};
      lv = (f16x4){(_Float16)(vb.x - (float)h0), (_Float16)(vb.y - (float)h1),
                   (_Float16)(vb.z - (float)h2), (_Float16)(vb.w - (float)h3)};
      *reinterpret_cast<f16x4*>(&Bh[rb[it]][kq * 4]) = hv;
      *reinterpret_cast<f16x4*>(&Bl[rb[it]][kq * 4]) = lv;
    }
    __syncthreads();
    const int kf = (lane >> 4) * 8;
    f16x8 ah[4], al[4], bh[4], bl[4];
    #pragma unroll
    for (int i = 0; i < 4; i++) {
      ah[i] = *reinterpret_cast<const f16x8*>(&Ah[wm + i * 16 + (lane & 15)][kf]);
      al[i] = *reinterpret_cast<const f16x8*>(&Al[wm + i * 16 + (lane & 15)][kf]);
    }
    #pragma unroll
    for (int j = 0; j < 4; j++) {
      bh[j] = *reinterpret_cast<const f16x8*>(&Bh[wn + j * 16 + (lane & 15)][kf]);
      bl[j] = *reinterpret_cast<const f16x8*>(&Bl[wn + j * 16 + (lane & 15)][kf]);
    }
    #pragma unroll
    for (int i = 0; i < 4; i++)
      #pragma unroll
      for (int j = 0; j < 4; j++) {
        acc[i][j] = __builtin_amdgcn_mfma_f32_16x16x32_f16(ah[i], bh[j], acc[i][j], 0, 0, 0);
        acc[i][j] = __builtin_amdgcn_mfma_f32_16x16x32_f16(ah[i], bl[j], acc[i][j], 0, 0, 0);
        acc[i][j] = __builtin_amdgcn_mfma_f32_16x16x32_f16(al[i], bh[j], acc[i][j], 0, 0, 0);
      }
    __syncthreads();
  }

  const size_t base = (size_t)bj * TT * SIMP;
  const int rq = (lane >> 4) * 4;                  // C/D: col=lane&15, row=(lane>>4)*4+q
  #pragma unroll
  for (int i = 0; i < 4; i++) {
    #pragma unroll
    for (int q = 0; q < 4; q++) {
      int n = m0 + wm + i * 16 + rq + q;
      if (n < TT) {
        #pragma unroll
        for (int j = 0; j < 4; j++) {
          int c = n0 + wn + j * 16 + (lane & 15);
          if (c < TT) sim[base + (size_t)n * SIMP + c] = acc[i][j][q];
        }
      }
    }
  }
}

// ---------- K3a: per row: thr, dis, adjacency bitmask (4 waves = 4 rows/block) ----------
__launch_bounds__(256)
__global__ void k_topk(const float* __restrict__ sim,
                       float* __restrict__ dis_o,
                       unsigned long long* __restrict__ mask_o) {
  const int l = threadIdx.x & 63, wv = threadIdx.x >> 6;
  const int r = blockIdx.x * 4 + wv;               // MM % 4 == 0
  const float* row = sim + (size_t)r * SIMP;
  float o0 = (l       < TT) ? row[l]       : NEG_INF;
  float o1 = (l + 64  < TT) ? row[l + 64]  : NEG_INF;
  float o2 = (l + 128 < TT) ? row[l + 128] : NEG_INF;
  float o3 = (l + 192 < TT) ? row[l + 192] : NEG_INF;
  float v0 = o0, v1 = o1, v2 = o2, v3 = o3;
  { float mx, mn;
    mx=fmaxf(v0,v1); mn=fminf(v0,v1); v0=mx; v1=mn;
    mx=fmaxf(v2,v3); mn=fminf(v2,v3); v2=mx; v3=mn;
    mx=fmaxf(v0,v2); mn=fminf(v0,v2); v0=mx; v2=mn;
    mx=fmaxf(v1,v3); mn=fminf(v1,v3); v1=mx; v3=mn;
    mx=fmaxf(v1,v2); mn=fminf(v1,v2); v1=mx; v2=mn; }
  int p = 0;
  float thr = NEG_INF;
  #pragma unroll
  for (int it = 0; it < 4; ++it) {
    float head = (p == 0) ? v0 : (p == 1) ? v1 : (p == 2) ? v2 : (p == 3) ? v3 : NEG_INF;
    float m = head;
    #pragma unroll
    for (int off = 1; off < 64; off <<= 1) m = fmaxf(m, __shfl_xor(m, off));
    thr = m;
    unsigned long long msk = __ballot(head == m);
    int first = __ffsll(msk) - 1;
    if (l == first) p++;
  }
  unsigned long long m0 = __ballot(o0 >= thr);
  unsigned long long m1 = __ballot(o1 >= thr);
  unsigned long long m2 = __ballot(o2 >= thr);
  unsigned long long m3 = __ballot(o3 >= thr);
  if (l == 0) {
    int deg = __popcll(m0) + __popcll(m1) + __popcll(m2) + __popcll(m3);
    dis_o[r] = rsqrtf((float)deg);
    mask_o[(size_t)r * 4 + 0] = m0;
    mask_o[(size_t)r * 4 + 1] = m1;
    mask_o[(size_t)r * 4 + 2] = m2;
    mask_o[(size_t)r * 4 + 3] = m3;
  }
}

// ---------- K3b: h = norm_adj @ v + u (one wave per row, 4 ch/lane) ----------
__launch_bounds__(512)
__global__ void k_agg(const unsigned long long* __restrict__ mask,
                      const float* __restrict__ dis, const unsigned short* __restrict__ u,
                      const unsigned short* __restrict__ v, unsigned short* __restrict__ h,
                      float* __restrict__ p1, float* __restrict__ p2) {
  __shared__ float dis_l[256];
  const int bj = blockIdx.x;
  const int tid = threadIdx.x, lane = tid & 63, wid = tid >> 6;
  if (tid < TT) dis_l[tid] = dis[(size_t)bj * TT + tid];
  __syncthreads();
  const int start = blockIdx.y * 122;
  const int cnt = blockIdx.y ? (TT - 122) : 122;
  const size_t pbase = (size_t)bj * TT;
  for (int rl = wid; rl < cnt; rl += 8) {
    const int t = start + rl;
    const size_t r = pbase + t;
    const float dr = dis_l[t];
    ushort4 uu = *reinterpret_cast<const ushort4*>(u + r * CC + lane * 4);
    float a0 = bf2f(uu.x), a1 = bf2f(uu.y), a2 = bf2f(uu.z), a3 = bf2f(uu.w);
    #pragma unroll
    for (int w4 = 0; w4 < 4; ++w4) {
      unsigned long long m = mask[r * 4 + w4];
      while (m) {
        int i = __ffsll(m) - 1;
        m &= m - 1;
        int idx = w4 * 64 + i;
        float w = dr * dis_l[idx];
        ushort4 vv = *reinterpret_cast<const ushort4*>(v + (pbase + idx) * CC + lane * 4);
        a0 = __builtin_fmaf(w, bf2f(vv.x), a0);
        a1 = __builtin_fmaf(w, bf2f(vv.y), a1);
        a2 = __builtin_fmaf(w, bf2f(vv.z), a2);
        a3 = __builtin_fmaf(w, bf2f(vv.w), a3);
      }
    }
    ushort4 hh;
    hh.x = f2bf(a0); hh.y = f2bf(a1); hh.z = f2bf(a2); hh.w = f2bf(a3);
    *reinterpret_cast<ushort4*>(h + r * CC + lane * 4) = hh;
    float s1 = a0 + a1 + a2 + a3;
    float s2 = a0*a0 + a1*a1 + a2*a2 + a3*a3;
    #pragma unroll
    for (int off = 1; off < 64; off <<= 1) { s1 += __shfl_xor(s1, off); s2 += __shfl_xor(s2, off); }
    if (lane == 0) { p1[r] = s1; p2[r] = s2; }
  }
}

// ---------- K4: BN stats per t -> scale/shift ----------
__global__ void k_bnstat(const float* __restrict__ p1, const float* __restrict__ p2,
                         const float* __restrict__ gamma, const float* __restrict__ beta,
                         float* __restrict__ scale, float* __restrict__ shift) {
  __shared__ float sA[256], sB[256];
  const int t = blockIdx.x;
  const int tid = threadIdx.x;
  float a = 0.f, b2 = 0.f;
  for (int bj = tid; bj < BJC; bj += 256) {
    a  += p1[bj * TT + t];
    b2 += p2[bj * TT + t];
  }
  sA[tid] = a; sB[tid] = b2;
  __syncthreads();
  for (int s = 128; s > 0; s >>= 1) {
    if (tid < s) { sA[tid] += sA[tid + s]; sB[tid] += sB[tid + s]; }
    __syncthreads();
  }
  if (tid == 0) {
    const float invN = 1.0f / (float)(BJC * CC);
    float mean = sA[0] * invN;
    float var  = sB[0] * invN - mean * mean;
    float sc   = rsqrtf(var + 1e-5f) * gamma[t];
    scale[t] = sc;
    shift[t] = beta[t] - mean * sc;
  }
}

// ---------- K5: out = relu(x + h*scale + shift), back to [B,T,J,C] ----------
__global__ void k_out(const float* __restrict__ x, const unsigned short* __restrict__ h,
                      const float* __restrict__ scale, const float* __restrict__ shift,
                      float* __restrict__ out) {
  int g = blockIdx.x * 256 + threadIdx.x;
  if (g >= MM * (CC/4)) return;
  int c4  = g & 63;
  int rowx = g >> 6;
  int b   = rowx / (TT*JJ);
  int rem = rowx - b*(TT*JJ);
  int t   = rem / JJ;
  int j   = rem - t*JJ;
  size_t hoff = ((size_t)(b*JJ + j) * TT + t) * CC + c4*4;
  float4 xv = *reinterpret_cast<const float4*>(x + (size_t)rowx*CC + c4*4);
  ushort4 hv = *reinterpret_cast<const ushort4*>(h + hoff);
  float sc = scale[t], sh = shift[t];
  float4 o;
  o.x = fmaxf(xv.x + bf2f(hv.x)*sc + sh, 0.f);
  o.y = fmaxf(xv.y + bf2f(hv.y)*sc + sh, 0.f);
  o.z = fmaxf(xv.z + bf2f(hv.z)*sc + sh, 0.f);
  o.w = fmaxf(xv.w + bf2f(hv.w)*sc + sh, 0.f);
  *reinterpret_cast<float4*>(out + (size_t)rowx*CC + c4*4) = o;
}

extern "C" void kernel_launch(void* const* d_in, const int* in_sizes, int n_in,
                              void* d_out, int out_size, void* d_ws, size_t ws_size,
                              hipStream_t stream) {
  const float* x     = (const float*)d_in[0];
  const float* Wu    = (const float*)d_in[1];
  const float* bu    = (const float*)d_in[2];
  const float* Wv    = (const float*)d_in[3];
  const float* bv    = (const float*)d_in[4];
  const float* gamma = (const float*)d_in[5];
  const float* beta  = (const float*)d_in[6];
  float* out = (float*)d_out;

  char* ws = (char*)d_ws;
  size_t off = 0;
  auto alloc = [&](size_t bytes) -> void* {
    void* p = ws + off;
    off = (off + bytes + 255) & ~(size_t)255;
    return p;
  };
  unsigned short* u   = (unsigned short*)alloc((size_t)MM * CC * 2);
  unsigned short* v   = (unsigned short*)alloc((size_t)MM * CC * 2);
  unsigned short* h   = (unsigned short*)alloc((size_t)MM * CC * 2);
  unsigned short* wc  = (unsigned short*)alloc((size_t)512 * CC * 2);
  float* sim = (float*)alloc((size_t)BJC * TT * SIMP * 4);
  float* dis = (float*)alloc((size_t)MM * 4);
  unsigned long long* msk = (unsigned long long*)alloc((size_t)MM * 4 * 8);
  float* p1    = (float*)alloc((size_t)MM * 4);
  float* p2    = (float*)alloc((size_t)MM * 4);
  float* scale = (float*)alloc(1024);
  float* shift = (float*)alloc(1024);

  if (ws_size < off) {
    hipMemsetAsync(d_out, 0, (size_t)out_size * 4, stream);
    return;
  }

  k_prep_w<<<dim3((512*(CC/4) + 255)/256), dim3(256), 0, stream>>>(Wu, Wv, wc);
  k_uv   <<<dim3((MM + 127)/128, 4), dim3(256), 0, stream>>>(x, wc, bu, bv, u, v);
  k_sim  <<<dim3(4, BJC), dim3(256), 0, stream>>>(x, sim);
  k_topk <<<dim3(MM/4), dim3(256), 0, stream>>>(sim, dis, msk);
  k_agg  <<<dim3(BJC, 2), dim3(512), 0, stream>>>(msk, dis, u, v, h, p1, p2);
  k_bnstat<<<dim3(TT), dim3(256), 0, stream>>>(p1, p2, gamma, beta, scale, shift);
  k_out  <<<dim3((MM*(CC/4) + 255)/256), dim3(256), 0, stream>>>(x, h, scale, shift, out);
}